// Round 3
// baseline (618.222 us; speedup 1.0000x reference)
//
#include <hip/hip_runtime.h>

// EDTAttention MI355X, round 5: kC fused into kB epilogue (per-wave LDS
// scratch proj-GEMM, direct f32 out writes -> kills 183MB amplified xhv
// write + kC's 201MB round trip), softmax rebuilt on 16-lane __shfl_xor
// (removes 2 LDS reduction trees + 4 of 6 barriers).
// Reg budget note: 64 VGPR + 64 AGPR acc2 = 128/wave = exactly 4 waves/SIMD
// (launch_bounds(1024,4)); epilogue accp must reuse retired acc2 regs.
//
// Index algebra (verified in earlier rounds):
//   Y[b,t,j] = xf @ qkv_w.T + qkv_b,  t = s*256+n, j in [0,256)
//   Q[b,h,s,d]  = Y[b, s*256 +       h*8+ns, j]   d = ns*256+j
//   K[b,h,s,d]  = Y[b, s*256 +  64 + h*8+ns, j]
//   VH[b,h,s,d] = Y[b, s*256 + 128 + h*8+ns, j]
//   VV[b,h,t,d] = Y[b, (h*32+d/64)*256 + 192 + (t/32)*8 + (t%32)/4, (t%4)*64 + d%64]
//   out token (b,s,n): n = h*32+db, all 64 c from one kB block -> proj fusable.

using half_t = _Float16;
using half8 = __attribute__((ext_vector_type(8))) _Float16;
using f32x4 = __attribute__((ext_vector_type(4))) float;

#define NTOK 524288      // 8*256*256

// async global->LDS, 16B per lane, LDS dest = wave-uniform base + lane*16
#define GLDS(g, l) __builtin_amdgcn_global_load_lds( \
    (const __attribute__((address_space(1))) void*)(g), \
    (__attribute__((address_space(3))) void*)(l), 16, 0, 0)

// ---- workspace layout (bytes) ----
#define WS_Q      0
#define WS_K      67108864
#define WS_VH     134217728
#define WS_VV     201326592
#define WS_NQ     335544320
#define WS_NK     335609856
#define WS_WH     335675392
#define WS_WP     335708160

// ---------------- weight prep: fp32 -> f16 ----------------
__global__ void kW0(const float* __restrict__ qkv_w, const float* __restrict__ proj_w,
                    half_t* __restrict__ Wh, half_t* __restrict__ Wp) {
    int tid = threadIdx.x;
    for (int i = tid; i < 256 * 64; i += 256) Wh[i] = (half_t)qkv_w[i];
    for (int i = tid; i < 64 * 64; i += 256) Wp[i] = (half_t)proj_w[i];
}

// ---------------- Y-tile MFMA core: acc[mt][i] over 64 tokens x 256 j, K=64 ----
__device__ inline void y_tile_mfma(const float* __restrict__ xb,
                                   const half_t* __restrict__ Wh,
                                   int tbase, int hi, int lo,
                                   f32x4 (&acc)[4][4], int wave, int lane) {
    const int l15 = lane & 15, quad = lane >> 4;
#pragma unroll
    for (int kc = 0; kc < 2; ++kc) {
        const int c = kc * 32 + quad * 8;
        half8 afr[4];
#pragma unroll
        for (int mt = 0; mt < 4; ++mt) {
            int m = mt * 16 + l15;
            int token = tbase + (m >> 3) * hi + (m & 7) * lo;
            const float* p = xb + (size_t)token * 64 + c;
            f32x4 f0 = *(const f32x4*)p;
            f32x4 f1 = *(const f32x4*)(p + 4);
            half8 a;
            a[0] = (half_t)f0[0]; a[1] = (half_t)f0[1]; a[2] = (half_t)f0[2]; a[3] = (half_t)f0[3];
            a[4] = (half_t)f1[0]; a[5] = (half_t)f1[1]; a[6] = (half_t)f1[2]; a[7] = (half_t)f1[3];
            afr[mt] = a;
        }
#pragma unroll
        for (int i = 0; i < 4; ++i) {
            int j = (wave * 4 + i) * 16 + l15;
            half8 bfr = *(const half8*)(Wh + j * 64 + c);
#pragma unroll
            for (int mt = 0; mt < 4; ++mt)
                acc[mt][i] = __builtin_amdgcn_mfma_f32_16x16x32_f16(afr[mt], bfr, acc[mt][i], 0, 0, 0);
        }
    }
}

// row-major dump: ylds[m][j], stride 264
__device__ inline void y_dump_rowmajor(f32x4 (&acc)[4][4], const float* __restrict__ qkv_b,
                                       half_t* ylds, int wave, int lane) {
    const int l15 = lane & 15, quad = lane >> 4;
#pragma unroll
    for (int i = 0; i < 4; ++i) {
        int j = (wave * 4 + i) * 16 + l15;
        float bj = qkv_b[j];
#pragma unroll
        for (int mt = 0; mt < 4; ++mt)
#pragma unroll
            for (int r = 0; r < 4; ++r)
                ylds[(mt * 16 + quad * 4 + r) * 264 + j] = (half_t)(acc[mt][i][r] + bj);
    }
}

// transposed dump: yldsT[j][m], stride 72
__device__ inline void y_dump_transposed(f32x4 (&acc)[4][4], const float* __restrict__ qkv_b,
                                         half_t* yldsT, int wave, int lane) {
    const int l15 = lane & 15, quad = lane >> 4;
#pragma unroll
    for (int i = 0; i < 4; ++i) {
        int j = (wave * 4 + i) * 16 + l15;
        float bj = qkv_b[j];
#pragma unroll
        for (int mt = 0; mt < 4; ++mt)
#pragma unroll
            for (int r = 0; r < 4; ++r)
                yldsT[j * 72 + mt * 16 + quad * 4 + r] = (half_t)(acc[mt][i][r] + bj);
    }
}

// ---------------- A1: Q and K (g=0,1) + norms ----------------
__global__ __launch_bounds__(256) void kA1(const float* __restrict__ x,
                                           const half_t* __restrict__ Wh,
                                           const float* __restrict__ qkv_b,
                                           half_t* __restrict__ Q, half_t* __restrict__ K,
                                           float* __restrict__ normQ, float* __restrict__ normK) {
    __shared__ half_t ylds[64 * 264];
    __shared__ float scr[256];
    int idx = blockIdx.x;
    int sb = idx & 31; idx >>= 5;
    int h = idx & 7; idx >>= 3;
    int g = idx & 1; int b = idx >> 1;
    int s0 = sb * 8;
    int n0 = g * 64 + h * 8;
    int tid = threadIdx.x, wave = tid >> 6, lane = tid & 63;
    const float* xb = x + (size_t)b * 65536 * 64;
    f32x4 acc[4][4];
#pragma unroll
    for (int a = 0; a < 4; ++a)
#pragma unroll
        for (int c = 0; c < 4; ++c) acc[a][c] = {0.f, 0.f, 0.f, 0.f};
    y_tile_mfma(xb, Wh, s0 * 256 + n0, 256, 1, acc, wave, lane);
    y_dump_rowmajor(acc, qkv_b, ylds, wave, lane);
    __syncthreads();
    half_t* dst = (g == 0 ? Q : K) + ((size_t)(b * 8 + h) * 256 + s0) * 2048;
    int ns = tid >> 5, jc = (tid & 31) * 8;
#pragma unroll
    for (int si = 0; si < 8; ++si) {
        half8 v = *(const half8*)&ylds[(si * 8 + ns) * 264 + jc];
        *(half8*)(dst + (size_t)si * 2048 + ns * 256 + jc) = v;
    }
    float sum = 0.f;
#pragma unroll
    for (int nn = 0; nn < 8; ++nn) {
        half8 v = *(const half8*)&ylds[((tid >> 5) * 8 + nn) * 264 + (tid & 31) * 8];
#pragma unroll
        for (int e = 0; e < 8; ++e) { float f = (float)v[e]; sum += f * f; }
    }
    scr[tid] = sum;
    __syncthreads();
    if (tid < 8) {
        float s = 0.f;
        for (int k2 = 0; k2 < 32; ++k2) s += scr[tid * 32 + k2];
        float* nd = (g == 0 ? normQ : normK);
        nd[(b * 8 + h) * 256 + s0 + tid] = s;
    }
}

// ---------------- A2H: V_H (g=2) -> VH[bh][d][t], wide stores ----------------
__global__ __launch_bounds__(256) void kA2H(const float* __restrict__ x,
                                            const half_t* __restrict__ Wh,
                                            const float* __restrict__ qkv_b,
                                            half_t* __restrict__ VH) {
    __shared__ half_t yldsT[256 * 72];
    int idx = blockIdx.x;
    int sb = idx & 3; idx >>= 2;
    int nn = idx & 63; int b = idx >> 6;
    int h = nn >> 3, ns = nn & 7;
    int n = 128 + nn;
    int s0 = sb * 64;
    int tid = threadIdx.x, wave = tid >> 6, lane = tid & 63;
    const float* xb = x + (size_t)b * 65536 * 64;
    f32x4 acc[4][4];
#pragma unroll
    for (int a = 0; a < 4; ++a)
#pragma unroll
        for (int c = 0; c < 4; ++c) acc[a][c] = {0.f, 0.f, 0.f, 0.f};
    y_tile_mfma(xb, Wh, s0 * 256 + n, 2048, 256, acc, wave, lane);  // m == local s
    y_dump_transposed(acc, qkv_b, yldsT, wave, lane);
    __syncthreads();
    int jl = lane >> 3, tc = lane & 7;
    half_t* base = VH + ((size_t)(b * 8 + h) * 2048 + ns * 256) * 256 + s0 + tc * 8;
#pragma unroll
    for (int u = 0; u < 8; ++u) {
        int j = wave * 64 + u * 8 + jl;
        half8 v = *(const half8*)&yldsT[j * 72 + tc * 8];
        *(half8*)(base + (size_t)j * 256) = v;
    }
}

// ---------------- A2V: V_V (g=3) -> VV[bh][d][t] (permuted), wide stores ------
__global__ __launch_bounds__(256) void kA2V(const float* __restrict__ x,
                                            const half_t* __restrict__ Wh,
                                            const float* __restrict__ qkv_b,
                                            half_t* __restrict__ VV) {
    __shared__ half_t yldsT[256 * 72];
    int idx = blockIdx.x;
    int st = idx & 255; int b = idx >> 8;
    int h = st >> 5;
    int tid = threadIdx.x, wave = tid >> 6, lane = tid & 63;
    const float* xb = x + (size_t)b * 65536 * 64;
    f32x4 acc[4][4];
#pragma unroll
    for (int a = 0; a < 4; ++a)
#pragma unroll
        for (int c = 0; c < 4; ++c) acc[a][c] = {0.f, 0.f, 0.f, 0.f};
    y_tile_mfma(xb, Wh, st * 256 + 192, 8, 1, acc, wave, lane);  // m == n-192
    y_dump_transposed(acc, qkv_b, yldsT, wave, lane);
    __syncthreads();
    // element (d = (st&31)*64 + dm, t) <- Y[m][(t&3)*64 + dm],
    //   m = (t>>5)*8 + ((t&31)>>2), t = wave*64 + tc*8 + e
    int dl = lane >> 3, tc = lane & 7;
    int mbase = wave * 16 + (tc >> 2) * 8 + (tc & 3) * 2;
    half_t* base = VV + ((size_t)(b * 8 + h) * 2048 + (st & 31) * 64) * 256 + wave * 64 + tc * 8;
#pragma unroll
    for (int u = 0; u < 8; ++u) {
        int dm = u * 8 + dl;
        half8 v;
#pragma unroll
        for (int e = 0; e < 8; ++e)
            v[e] = yldsT[((e & 3) * 64 + dm) * 72 + mbase + (e >> 2)];
        *(half8*)(base + (size_t)dm * 256) = v;
    }
}

// ---------------- B: fused cosine attention + output projection --------------
// QBLK=64, 256 blocks x 1024 thr. Pass 1 LDS-staged dbuf GEMM (round-4).
// Softmax: 16-lane shuffle reduce (no LDS trees, no extra barriers).
// Epilogue: per-wave proj GEMM via LDS scratch (reuses dead Ks region),
// writes f32 out directly -> kC eliminated.
__global__ __launch_bounds__(1024, 4) void kB(const half_t* __restrict__ Q, const half_t* __restrict__ K,
                                              const half_t* __restrict__ VH, const half_t* __restrict__ VV,
                                              const float* __restrict__ normQ, const float* __restrict__ normK,
                                              const float* __restrict__ temp1, const float* __restrict__ temp2,
                                              const half_t* __restrict__ Wp, const float* __restrict__ proj_b,
                                              float* __restrict__ out) {
    extern __shared__ char smem[];
    char* Ks0 = smem;                            // [256][64] halfs, 32768B (pass-1 only)
    char* Ks1 = smem + 32768;                    // 32768B (pass-1 only)
    char* Qs0 = smem + 65536;                    // [64][64] halfs, 8192B (pass-1 only)
    char* Qs1 = smem + 73728;                    // 8192B (pass-1 only)
    // per-wave epilogue scratch overlaps dead Ks region: 16x72 halfs = 2304B/wave
    half_t* scratch = (half_t*)smem;
    half_t* PH = (half_t*)(smem + 81920);        // [64][264]
    half_t* PV = (half_t*)(smem + 115712);       // [64][264] -> 149504
    float* rq  = (float*)(smem + 149504);        // [64]
    float* rk  = (float*)(smem + 149760);        // [256] -> end 150784

    int idx = blockIdx.x;
    int bh = idx & 63;              // XCD swizzle: same-bh sq-siblings share XCD
    int sqb = idx >> 6;             // 0..3
    int h = bh & 7, b = bh >> 3;
    int sq0 = sqb * 64;
    int tid = threadIdx.x, wave = tid >> 6, lane = tid & 63;
    int l15 = lane & 15, quad = lane >> 4;
    float t1 = temp1[h], t2 = temp2[h];
    const half_t* Qb = Q + (size_t)bh * 256 * 2048;
    const half_t* Kb = K + (size_t)bh * 256 * 2048;
    const half_t* VHb = VH + (size_t)bh * 2048 * 256;
    const half_t* VVb = VV + (size_t)bh * 2048 * 256;

    if (tid < 64) rq[tid] = 1.f / fmaxf(sqrtf(normQ[bh * 256 + sq0 + tid]), 1e-12f);
    if (tid < 256) rk[tid] = 1.f / fmaxf(sqrtf(normK[bh * 256 + tid]), 1e-12f);

    // ---- pass 1: sim = Q.K^T (64 x 256), LDS-staged. wave w owns t-tile w*16 ----
    {
        const int l7 = lane & 7, l8 = lane >> 3;
        // pre-swizzled global source: LDS slot (row r, s) holds global col16 s^(r&7).
        const int swzh = (l7 ^ (l8 & 7)) * 8;     // halfs offset within 64-half row
        const half_t* gK0 = Kb + (size_t)(wave * 8 + l8) * 2048 + swzh;         // rows [w*8, +8)
        const half_t* gK1 = Kb + (size_t)(128 + wave * 8 + l8) * 2048 + swzh;   // rows [128+w*8, +8)
        const half_t* gQ  = Qb + (size_t)(sq0 + (wave & 7) * 8 + l8) * 2048 + swzh;

        auto STAGE = [&](int kk, char* KsB, char* QsB) {
            const int off = kk * 64;              // BK=64 halfs per step
            GLDS(gK0 + off, KsB + wave * 1024);
            GLDS(gK1 + off, KsB + 16384 + wave * 1024);
            if (wave < 8) GLDS(gQ + off, QsB + wave * 1024);
        };

        f32x4 acc1[4];
#pragma unroll
        for (int a = 0; a < 4; ++a) acc1[a] = {0.f, 0.f, 0.f, 0.f};
        const int tcol = wave * 16 + l15;
        const int ts7 = tcol & 7;

        auto COMPUTE = [&](const char* KsB_, const char* QsB_) {
            const half_t* KsB = (const half_t*)KsB_;
            const half_t* QsB = (const half_t*)QsB_;
#pragma unroll
            for (int sub = 0; sub < 2; ++sub) {
                int c16 = sub * 4 + quad;         // 16B-slot index = d-slice
                half8 bfr = *(const half8*)(KsB + tcol * 64 + (c16 ^ ts7) * 8);
#pragma unroll
                for (int mt = 0; mt < 4; ++mt) {
                    int m = mt * 16 + l15;
                    half8 afr = *(const half8*)(QsB + m * 64 + (c16 ^ (m & 7)) * 8);
                    acc1[mt] = __builtin_amdgcn_mfma_f32_16x16x32_f16(afr, bfr, acc1[mt], 0, 0, 0);
                }
            }
        };

        STAGE(0, Ks0, Qs0);
        __syncthreads();                          // drains vmcnt -> buf0 ready (also rq/rk)
        for (int kk = 0; kk < 32; kk += 2) {
            if (kk + 1 < 32) STAGE(kk + 1, Ks1, Qs1);
            COMPUTE(Ks0, Qs0);
            __syncthreads();                      // buf1 staged + buf0 consumed
            if (kk + 2 < 32) STAGE(kk + 2, Ks0, Qs0);
            COMPUTE(Ks1, Qs1);
            __syncthreads();
        }
        float rkt = rk[tcol];
#pragma unroll
        for (int mt = 0; mt < 4; ++mt)
#pragma unroll
            for (int r = 0; r < 4; ++r) {
                int row = mt * 16 + quad * 4 + r;
                PH[row * 264 + tcol] = (half_t)(acc1[mt][r] * rq[row] * rkt);
            }
    }
    __syncthreads();

    // ---- dual softmax: thread owns (row = tid>>4, chunk = tid&15); the 16
    // reducers of a row are contiguous lanes -> pure shuffle reduction ----
    {
        int r_ = tid >> 4, cc = tid & 15;
        half_t* phrow = &PH[r_ * 264 + cc * 16];
        half_t* pvrow = &PV[r_ * 264 + cc * 16];
        half8 v0 = *(const half8*)phrow;
        half8 v1 = *(const half8*)(phrow + 8);
        float fv[16];
#pragma unroll
        for (int e = 0; e < 8; ++e) { fv[e] = (float)v0[e]; fv[8 + e] = (float)v1[e]; }
        float mx = fv[0], mn = fv[0];
#pragma unroll
        for (int e = 1; e < 16; ++e) { mx = fmaxf(mx, fv[e]); mn = fminf(mn, fv[e]); }
#pragma unroll
        for (int m = 1; m < 16; m <<= 1) {
            mx = fmaxf(mx, __shfl_xor(mx, m, 16));
            mn = fminf(mn, __shfl_xor(mn, m, 16));
        }
        float mh = (t1 >= 0.f) ? t1 * mx : t1 * mn;
        float mv = (t2 >= 0.f) ? t2 * mx : t2 * mn;
        float sh = 0.f, sv = 0.f;
#pragma unroll
        for (int e = 0; e < 16; ++e) {
            sh += __expf(fv[e] * t1 - mh);
            sv += __expf(fv[e] * t2 - mv);
        }
#pragma unroll
        for (int m = 1; m < 16; m <<= 1) {
            sh += __shfl_xor(sh, m, 16);
            sv += __shfl_xor(sv, m, 16);
        }
        float rh = 1.f / sh, rv = 1.f / sv;
        half8 o0, o1, p0, p1;
#pragma unroll
        for (int e = 0; e < 8; ++e) {
            o0[e] = (half_t)(__expf(fv[e] * t1 - mh) * rh);
            o1[e] = (half_t)(__expf(fv[8 + e] * t1 - mh) * rh);
            p0[e] = (half_t)(__expf(fv[e] * t2 - mv) * rv);
            p1[e] = (half_t)(__expf(fv[8 + e] * t2 - mv) * rv);
        }
        *(half8*)phrow = o0; *(half8*)(phrow + 8) = o1;
        *(half8*)pvrow = p0; *(half8*)(pvrow + 8) = p1;
    }
    __syncthreads();

    // ---- pass 2 + fused proj: wave w owns d-chunks w*64, w*64+1024 ----
    half_t* myscr = scratch + wave * 1152;       // 16 rows x 72 halfs = 2304B
    float bj[4];
#pragma unroll
    for (int jt = 0; jt < 4; ++jt) bj[jt] = proj_b[jt * 16 + l15];

#pragma unroll
    for (int i2 = 0; i2 < 2; ++i2) {
        int d0 = wave * 64 + i2 * 1024;
        f32x4 acc2[4][4];
#pragma unroll
        for (int a = 0; a < 4; ++a)
#pragma unroll
            for (int c = 0; c < 4; ++c) acc2[a][c] = {0.f, 0.f, 0.f, 0.f};
        for (int kc = 0; kc < 8; ++kc) {
            int tk = kc * 32 + quad * 8;
            half8 afr[4];
#pragma unroll
            for (int mt = 0; mt < 4; ++mt)
                afr[mt] = *(const half8*)&PH[(mt * 16 + l15) * 264 + tk];
#pragma unroll
            for (int nt = 0; nt < 4; ++nt) {
                half8 bfr = *(const half8*)(VHb + (size_t)(d0 + nt * 16 + l15) * 256 + tk);
#pragma unroll
                for (int mt = 0; mt < 4; ++mt)
                    acc2[mt][nt] = __builtin_amdgcn_mfma_f32_16x16x32_f16(afr[mt], bfr, acc2[mt][nt], 0, 0, 0);
            }
#pragma unroll
            for (int mt = 0; mt < 4; ++mt)
                afr[mt] = *(const half8*)&PV[(mt * 16 + l15) * 264 + tk];
#pragma unroll
            for (int nt = 0; nt < 4; ++nt) {
                half8 bfr = *(const half8*)(VVb + (size_t)(d0 + nt * 16 + l15) * 256 + tk);
#pragma unroll
                for (int mt = 0; mt < 4; ++mt)
                    acc2[mt][nt] = __builtin_amdgcn_mfma_f32_16x16x32_f16(afr[mt], bfr, acc2[mt][nt], 0, 0, 0);
            }
        }
        // ---- fused projection epilogue: per mt, 16 rows x 64 c -> 64 j ----
        int db = wave + i2 * 16;   // d0/64 in [0,32)
#pragma unroll
        for (int mt = 0; mt < 4; ++mt) {
            // dump this mt's 16x64 half tile to per-wave scratch (stride 72)
#pragma unroll
            for (int nt = 0; nt < 4; ++nt)
#pragma unroll
                for (int r = 0; r < 4; ++r)
                    myscr[(quad * 4 + r) * 72 + nt * 16 + l15] = (half_t)acc2[mt][nt][r];
            // proj GEMM: A = scratch rows (s), B = Wp[j][c], K = c = 64
            f32x4 accp[4];
#pragma unroll
            for (int jt = 0; jt < 4; ++jt) accp[jt] = {0.f, 0.f, 0.f, 0.f};
#pragma unroll
            for (int kc2 = 0; kc2 < 2; ++kc2) {
                half8 afr = *(const half8*)&myscr[l15 * 72 + kc2 * 32 + quad * 8];
#pragma unroll
                for (int jt = 0; jt < 4; ++jt) {
                    half8 bfr = *(const half8*)(Wp + (jt * 16 + l15) * 64 + kc2 * 32 + quad * 8);
                    accp[jt] = __builtin_amdgcn_mfma_f32_16x16x32_f16(afr, bfr, accp[jt], 0, 0, 0);
                }
            }
#pragma unroll
            for (int jt = 0; jt < 4; ++jt)
#pragma unroll
                for (int r = 0; r < 4; ++r) {
                    int srow = mt * 16 + quad * 4 + r;
                    size_t token = (size_t)b * 65536 + (size_t)(sq0 + srow) * 256 + h * 32 + db;
                    out[token * 64 + jt * 16 + l15] = accp[jt][r] + bj[jt];
                }
        }
    }
}

extern "C" void kernel_launch(void* const* d_in, const int* in_sizes, int n_in,
                              void* d_out, int out_size, void* d_ws, size_t ws_size,
                              hipStream_t stream) {
    const float* x      = (const float*)d_in[0];
    const float* qkv_w  = (const float*)d_in[1];
    const float* qkv_b  = (const float*)d_in[2];
    const float* proj_w = (const float*)d_in[3];
    const float* proj_b = (const float*)d_in[4];
    const float* temp1  = (const float*)d_in[5];
    const float* temp2  = (const float*)d_in[6];
    char* ws = (char*)d_ws;
    half_t* Q   = (half_t*)(ws + WS_Q);
    half_t* K   = (half_t*)(ws + WS_K);
    half_t* VH  = (half_t*)(ws + WS_VH);
    half_t* VV  = (half_t*)(ws + WS_VV);
    float* normQ = (float*)(ws + WS_NQ);
    float* normK = (float*)(ws + WS_NK);
    half_t* Wh  = (half_t*)(ws + WS_WH);
    half_t* Wp  = (half_t*)(ws + WS_WP);
    float* out = (float*)d_out;

    hipFuncSetAttribute((const void*)kB, hipFuncAttributeMaxDynamicSharedMemorySize, 150784);

    kW0<<<1, 256, 0, stream>>>(qkv_w, proj_w, Wh, Wp);
    kA1<<<4096, 256, 0, stream>>>(x, Wh, qkv_b, Q, K, normQ, normK);
    kA2H<<<2048, 256, 0, stream>>>(x, Wh, qkv_b, VH);
    kA2V<<<2048, 256, 0, stream>>>(x, Wh, qkv_b, VV);
    kB<<<256, 1024, 150784, stream>>>(Q, K, VH, VV, normQ, normK, temp1, temp2,
                                      Wp, proj_b, out);
}